// Round 15
// baseline (223.743 us; speedup 1.0000x reference)
//
#include <hip/hip_runtime.h>

#define N_NODES 100000
#define E_EDGES 1600000
#define D 128
#define PAD 136            // LDS row stride (ushorts) for GEMM tiles
#define GEMM_BLKS 1563     // (N+63)/64
#define SCHUNK 8192        // edges per scatter block (512 threads, 16/thread)
#define SCAT_BLKS ((E_EDGES + SCHUNK - 1) / SCHUNK)   // 196
#define RANGE 98           // nodes per dst-range
#define NR 1024            // 1024*98 = 100352 >= N
#define RCAP 2048          // fixed ebuf region per range (mean 1562, sigma 39.5 -> +12 sigma safe)
#define CAP 2048           // k_agg chunk capacity == RCAP (single chunk guaranteed)
#define NPW 13             // nodes per wave in k_agg: ceil(98/8)

typedef __attribute__((ext_vector_type(8))) short short8;
typedef __attribute__((ext_vector_type(8))) unsigned short ushort8v;
typedef __attribute__((ext_vector_type(4))) float f32x4;

// ---------- threefry2x32, key=(0,42), ctr=(0,i); JAX partitionable 32-bit: x0^x1 ----------
__device__ __forceinline__ unsigned int rotl32(unsigned int x, int r) {
  return (x << r) | (x >> (32 - r));
}

__device__ __forceinline__ unsigned int threefry_bits(unsigned int ctr) {
  const unsigned int ks0 = 0u, ks1 = 42u;
  const unsigned int ks2 = ks0 ^ ks1 ^ 0x1BD11BDAu;
  unsigned int x0 = ks0;
  unsigned int x1 = ctr + ks1;
#define TF_ROUND(R) { x0 += x1; x1 = rotl32(x1, R); x1 ^= x0; }
  TF_ROUND(13) TF_ROUND(15) TF_ROUND(26) TF_ROUND(6)
  x0 += ks1; x1 += ks2 + 1u;
  TF_ROUND(17) TF_ROUND(29) TF_ROUND(16) TF_ROUND(24)
  x0 += ks2; x1 += ks0 + 2u;
  TF_ROUND(13) TF_ROUND(15) TF_ROUND(26) TF_ROUND(6)
  x0 += ks0; x1 += ks1 + 3u;
  TF_ROUND(17) TF_ROUND(29) TF_ROUND(16) TF_ROUND(24)
  x0 += ks1; x1 += ks2 + 4u;
  TF_ROUND(13) TF_ROUND(15) TF_ROUND(26) TF_ROUND(6)
  x0 += ks2; x1 += ks0 + 5u;
#undef TF_ROUND
  return x0 ^ x1;
}

__device__ __forceinline__ unsigned short f2bf(float f) {
  unsigned int u = __float_as_uint(f);
  u = (u + 0x7FFFu + ((u >> 16) & 1u)) >> 16;   // RNE
  return (unsigned short)u;
}
__device__ __forceinline__ float bf2f_lo(unsigned int v) {
  return __uint_as_float(v << 16);
}
__device__ __forceinline__ float bf2f_hi(unsigned int v) {
  return __uint_as_float(v & 0xFFFF0000u);
}

// ---------- init: convert W to bf16 [n][k] + init range cursors to region starts ----------
__global__ __launch_bounds__(256) void k_init(const float* __restrict__ w,
                                              unsigned short* __restrict__ wbf,
                                              int* __restrict__ cur) {
  int t = blockIdx.x * 256 + threadIdx.x;     // 64*256 = 16384 = 128*128
  int k = t >> 7;          // w is [k][n] row-major
  int n = t & 127;
  wbf[n * 128 + k] = f2bf(w[t]);
  if (t < NR) cur[t] = t * RCAP;
}

// ---------- scatter: 2-pass per 8192-edge chunk; pass-1 rank reused (no 2nd atomic round) ----------
__global__ __launch_bounds__(512) void k_scat(const int* __restrict__ ei,
                                              int* __restrict__ cur,
                                              int* __restrict__ ebuf) {
  __shared__ int lcnt[NR];
  __shared__ int gb[NR];
  const int t = threadIdx.x;
  const int e0 = blockIdx.x * SCHUNK;
  for (int i = t; i < NR; i += 512) lcnt[i] = 0;
  __syncthreads();
  // pass 1: per-range histogram; keep dst AND rank in regs for pass 2
  int myd[SCHUNK / 512];
  int myr[SCHUNK / 512];
#pragma unroll
  for (int i = 0; i < SCHUNK / 512; ++i) {
    int e = e0 + i * 512 + t;
    myd[i] = -1;
    if (e < E_EDGES) {
      int d = ei[E_EDGES + e];
      myd[i] = d;
      myr[i] = atomicAdd(&lcnt[d / RANGE], 1);
    }
  }
  __syncthreads();
  // claim one contiguous run per live range (returning global atomic)
  for (int i = t; i < NR; i += 512) {
    int c = lcnt[i];
    gb[i] = c ? atomicAdd(&cur[i], c) : 0;
  }
  __syncthreads();
  // pass 2: place at base + pass-1 rank (no second LDS-atomic pass)
#pragma unroll
  for (int i = 0; i < SCHUNK / 512; ++i) {
    int d = myd[i];
    if (d >= 0) {
      int e = e0 + i * 512 + t;
      int s = ei[e];
      int b = d / RANGE;
      int dl = d - b * RANGE;
      int pos = gb[b] + myr[i];
      if (pos < (b + 1) * RCAP)              // defensive clamp (statistically impossible)
        ebuf[pos] = s | (dl << 17);          // src: 17 bits, dst_local: 7 bits
    }
  }
}

// ---------- fused: degrees (blocks < NR, ebuf still L2-hot) + gemm (rest) ----------
__global__ __launch_bounds__(256) void k_dg(const float* __restrict__ x,
                                            const unsigned short* __restrict__ wbf,
                                            unsigned short* __restrict__ h,
                                            const int* __restrict__ ebuf,
                                            const int* __restrict__ cur,
                                            float* __restrict__ dinv) {
  __shared__ unsigned short Wl[128 * PAD];   // [n][k]
  __shared__ unsigned short Xl[64 * PAD];    // [m][k]; bounce; deg branch aliases
  const int t = threadIdx.x;

  if (blockIdx.x < NR) {
    // ---- deg branch: per-range LDS histogram (exclusive ownership, int atomics) ----
    int* hist = (int*)Xl;
    const int r = blockIdx.x;
    if (t < 128) hist[t] = 0;
    __syncthreads();
    const int lo = r * RCAP;
    const int hi = min(cur[r], lo + RCAP);
    for (int e = lo + t; e < hi; e += 256)
      atomicAdd(&hist[((unsigned)ebuf[e]) >> 17], 1);
    __syncthreads();
    if (t < RANGE) {
      int n = r * RANGE + t;
      if (n < N_NODES) dinv[n] = rsqrtf((float)(hist[t] + 1));
    }
    return;
  }

  const int row0 = (blockIdx.x - NR) * 64;

  // stage W from pre-converted bf16: 16B/lane, coalesced
#pragma unroll
  for (int i = 0; i < 8; ++i) {
    int u  = t + i * 256;        // 0..2047 16B-units
    int kg = u & 15;
    int n  = u >> 4;             // 0..127
    *(ushort8v*)&Wl[n * PAD + kg * 8] = *(const ushort8v*)&wbf[n * 128 + kg * 8];
  }
  // stage X: 64 rows x 128 k, f32 -> bf16
  const float4* x4 = (const float4*)x;
#pragma unroll
  for (int i = 0; i < 8; ++i) {
    int id = t + i * 256;
    int r  = id >> 5;
    int c4 = id & 31;
    int row = row0 + r; if (row >= N_NODES) row = N_NODES - 1;
    float4 v = x4[(long long)row * 32 + c4];
    ushort4 p;
    p.x = f2bf(v.x); p.y = f2bf(v.y); p.z = f2bf(v.z); p.w = f2bf(v.w);
    *(ushort4*)&Xl[r * PAD + c4 * 4] = p;
  }
  __syncthreads();

  const int wv   = t >> 6;
  const int l    = t & 63;
  const int quad = l >> 4;
  const int ln16 = l & 15;
  const int m0   = wv * 16;

  short8 a[4];
#pragma unroll
  for (int kt = 0; kt < 4; ++kt)
    a[kt] = *(const short8*)&Xl[(m0 + ln16) * PAD + kt * 32 + quad * 8];

#pragma unroll
  for (int nt = 0; nt < 8; ++nt) {
    f32x4 acc = {0.f, 0.f, 0.f, 0.f};
#pragma unroll
    for (int kt = 0; kt < 4; ++kt) {
      short8 b = *(const short8*)&Wl[(nt * 16 + ln16) * PAD + kt * 32 + quad * 8];
      acc = __builtin_amdgcn_mfma_f32_16x16x32_bf16(a[kt], b, acc, 0, 0, 0);
    }
#pragma unroll
    for (int r = 0; r < 4; ++r)
      Xl[(m0 + quad * 4 + r) * PAD + nt * 16 + ln16] = f2bf(acc[r]);
  }

  // coalesced writeback: 16 lanes cover one 256B h row
#pragma unroll
  for (int v = 0; v < 4; ++v) {
    int idx = v * 64 + l;        // 0..255
    int rr  = idx >> 4;
    int ch  = idx & 15;
    int row = row0 + m0 + rr;
    if (row < N_NODES)
      *(ushort8v*)&h[(long long)row * D + ch * 8] = *(const ushort8v*)&Xl[(m0 + rr) * PAD + ch * 8];
  }
}

// ---------- aggregate: LDS counting-sort by dst_local, register accumulation ----------
// dinv[src] prefetched during the load phase (overlaps hist/scan barriers) and packed
// with src into int2 sswp -> inner loop is ds_read_b64 -> h-load -> fma (one global dep).
__global__ __launch_bounds__(512) void k_agg(const int* __restrict__ ebuf,
                                             const int* __restrict__ cur,
                                             const float* __restrict__ dinv,
                                             const unsigned short* __restrict__ h,
                                             const float* __restrict__ bias,
                                             float* __restrict__ out) {
  __shared__ int2 sswp[CAP];      // 16 KB (src, dinv_bits)
  __shared__ int shist[128];
  __shared__ int sscn[128];
  __shared__ int scur[128];
  const int t  = threadIdx.x;
  const int r  = blockIdx.x;
  const int wv = t >> 6;
  const int l  = t & 63;
  const unsigned int* h32 = (const unsigned int*)h;

  float a0[NPW], a1[NPW];
#pragma unroll
  for (int j = 0; j < NPW; ++j) { a0[j] = 0.f; a1[j] = 0.f; }

  const int lo = r * RCAP;
  const int m  = min(cur[r], lo + RCAP) - lo;   // 0..2048, single chunk

  if (t < 128) shist[t] = 0;
  __syncthreads();

  // load packed edges + prefetch src dinv (random L2 gather hides under hist/scan) + histogram
  int pk0 = -1, pk1 = -1, pk2 = -1, pk3 = -1;
  float w0 = 0.f, w1 = 0.f, w2 = 0.f, w3 = 0.f;
  {
    int i0 = t, i1 = t + 512, i2 = t + 1024, i3 = t + 1536;
    if (i0 < m) { pk0 = ebuf[lo + i0]; w0 = dinv[pk0 & 0x1FFFF]; atomicAdd(&shist[((unsigned)pk0) >> 17], 1); }
    if (i1 < m) { pk1 = ebuf[lo + i1]; w1 = dinv[pk1 & 0x1FFFF]; atomicAdd(&shist[((unsigned)pk1) >> 17], 1); }
    if (i2 < m) { pk2 = ebuf[lo + i2]; w2 = dinv[pk2 & 0x1FFFF]; atomicAdd(&shist[((unsigned)pk2) >> 17], 1); }
    if (i3 < m) { pk3 = ebuf[lo + i3]; w3 = dinv[pk3 & 0x1FFFF]; atomicAdd(&shist[((unsigned)pk3) >> 17], 1); }
  }
  __syncthreads();

  // inclusive scan over 128 buckets (98 live)
  if (t < 128) sscn[t] = shist[t];
  __syncthreads();
  for (int off = 1; off < 128; off <<= 1) {
    int xv = (t < 128 && t >= off) ? sscn[t - off] : 0;
    __syncthreads();
    if (t < 128) sscn[t] += xv;
    __syncthreads();
  }
  if (t < 128) scur[t] = sscn[t] - shist[t];   // exclusive start
  __syncthreads();

  // scatter (src, dinv_bits) into sorted position (native int LDS atomics)
  if (pk0 != -1) sswp[atomicAdd(&scur[((unsigned)pk0) >> 17], 1)] = make_int2(pk0 & 0x1FFFF, __float_as_int(w0));
  if (pk1 != -1) sswp[atomicAdd(&scur[((unsigned)pk1) >> 17], 1)] = make_int2(pk1 & 0x1FFFF, __float_as_int(w1));
  if (pk2 != -1) sswp[atomicAdd(&scur[((unsigned)pk2) >> 17], 1)] = make_int2(pk2 & 0x1FFFF, __float_as_int(w2));
  if (pk3 != -1) sswp[atomicAdd(&scur[((unsigned)pk3) >> 17], 1)] = make_int2(pk3 & 0x1FFFF, __float_as_int(w3));
  __syncthreads();

  // per-node register accumulation; segments from scan
#pragma unroll
  for (int j = 0; j < NPW; ++j) {
    int nl = wv + 8 * j;
    if (nl < RANGE) {
      int s1i = sscn[nl];
      int s0i = s1i - shist[nl];
      float aa0 = a0[j], aa1 = a1[j];
#pragma unroll 4
      for (int e = s0i; e < s1i; ++e) {
        int2 p = sswp[e];                      // wave-uniform LDS broadcast (b64)
        float wgt = __int_as_float(p.y);
        unsigned u = h32[(long long)p.x * 64 + l];
        aa0 = fmaf(bf2f_lo(u), wgt, aa0);
        aa1 = fmaf(bf2f_hi(u), wgt, aa1);
      }
      a0[j] = aa0; a1[j] = aa1;
    }
  }

  // finalize: out = dinv_n*(acc + dinv_n*h_n) + bias, relu, dropout
  // dv recomputed from shist (own-range degree) - no global dinv re-read
#pragma unroll
  for (int j = 0; j < NPW; ++j) {
    int nl = wv + 8 * j;
    if (nl >= RANGE) continue;
    int n = r * RANGE + nl;
    if (n >= N_NODES) continue;
    float dv = rsqrtf((float)(shist[nl] + 1));
    unsigned hv = h32[(long long)n * 64 + l];
    float v0 = (a0[j] + bf2f_lo(hv) * dv) * dv;
    float v1 = (a1[j] + bf2f_hi(hv) * dv) * dv;
    float2 bb = ((const float2*)bias)[l];
    float r0 = fmaxf(v0 + bb.x, 0.f);
    float r1 = fmaxf(v1 + bb.y, 0.f);
    unsigned i0 = (unsigned)n * 128u + (unsigned)(2 * l);
    unsigned b0 = threefry_bits(i0);
    unsigned b1 = threefry_bits(i0 + 1u);
    float2 res;
    res.x = (b0 & 0x80000000u) ? 0.0f : r0 * 2.0f;
    res.y = (b1 & 0x80000000u) ? 0.0f : r1 * 2.0f;
    ((float2*)out)[(long long)n * 64 + l] = res;
  }
}

extern "C" void kernel_launch(void* const* d_in, const int* in_sizes, int n_in,
                              void* d_out, int out_size, void* d_ws, size_t ws_size,
                              hipStream_t stream) {
  const float* x    = (const float*)d_in[0];
  const int*   ei   = (const int*)d_in[1];
  const float* w    = (const float*)d_in[2];
  const float* bias = (const float*)d_in[3];
  float* out = (float*)d_out;

  char* p = (char*)d_ws;
  unsigned short* h   = (unsigned short*)p;  p += (size_t)N_NODES * D * 2;   // 25.6 MB
  unsigned short* wbf = (unsigned short*)p;  p += 128 * 128 * 2;             // 32 KB
  float* dinv = (float*)p;                   p += (size_t)(NR * RANGE) * 4;  // 401 KB
  int* cur    = (int*)p;                     p += NR * 4;                    // 4 KB
  int* ebuf   = (int*)p;                     p += (size_t)NR * RCAP * 4;     // 8.4 MB

  k_init<<<64, 256, 0, stream>>>(w, wbf, cur);
  k_scat<<<SCAT_BLKS, 512, 0, stream>>>(ei, cur, ebuf);
  k_dg<<<NR + GEMM_BLKS, 256, 0, stream>>>(x, wbf, h, ebuf, cur, dinv);
  k_agg<<<NR, 512, 0, stream>>>(ebuf, cur, dinv, h, bias, out);
}

// Round 16
// 215.892 us; speedup vs baseline: 1.0364x; 1.0364x over previous
//
#include <hip/hip_runtime.h>

#define N_NODES 100000
#define E_EDGES 1600000
#define D 128
#define PAD 136            // LDS row stride (ushorts) for GEMM tiles
#define GEMM_BLKS 1563     // (N+63)/64
#define SCHUNK 4096        // edges per scatter block
#define SCAT_BLKS ((E_EDGES + SCHUNK - 1) / SCHUNK)   // 391
#define WCONV_BLKS 64      // wbf-convert blocks fused into scat launch
#define RANGE 98           // nodes per dst-range
#define NR 1024            // 1024*98 = 100352 >= N
#define RCAP 2048          // fixed ebuf region per range (mean 1562, sigma 39.5 -> +12 sigma safe)
#define CAP 2048           // k_agg chunk capacity == RCAP (single chunk guaranteed)
#define NPW 13             // nodes per wave in k_agg: ceil(98/8)

typedef __attribute__((ext_vector_type(8))) short short8;
typedef __attribute__((ext_vector_type(8))) unsigned short ushort8v;
typedef __attribute__((ext_vector_type(4))) float f32x4;

// ---------- threefry2x32, key=(0,42), ctr=(0,i); JAX partitionable 32-bit: x0^x1 ----------
__device__ __forceinline__ unsigned int rotl32(unsigned int x, int r) {
  return (x << r) | (x >> (32 - r));
}

__device__ __forceinline__ unsigned int threefry_bits(unsigned int ctr) {
  const unsigned int ks0 = 0u, ks1 = 42u;
  const unsigned int ks2 = ks0 ^ ks1 ^ 0x1BD11BDAu;
  unsigned int x0 = ks0;
  unsigned int x1 = ctr + ks1;
#define TF_ROUND(R) { x0 += x1; x1 = rotl32(x1, R); x1 ^= x0; }
  TF_ROUND(13) TF_ROUND(15) TF_ROUND(26) TF_ROUND(6)
  x0 += ks1; x1 += ks2 + 1u;
  TF_ROUND(17) TF_ROUND(29) TF_ROUND(16) TF_ROUND(24)
  x0 += ks2; x1 += ks0 + 2u;
  TF_ROUND(13) TF_ROUND(15) TF_ROUND(26) TF_ROUND(6)
  x0 += ks0; x1 += ks1 + 3u;
  TF_ROUND(17) TF_ROUND(29) TF_ROUND(16) TF_ROUND(24)
  x0 += ks1; x1 += ks2 + 4u;
  TF_ROUND(13) TF_ROUND(15) TF_ROUND(26) TF_ROUND(6)
  x0 += ks2; x1 += ks0 + 5u;
#undef TF_ROUND
  return x0 ^ x1;
}

__device__ __forceinline__ unsigned short f2bf(float f) {
  unsigned int u = __float_as_uint(f);
  u = (u + 0x7FFFu + ((u >> 16) & 1u)) >> 16;   // RNE
  return (unsigned short)u;
}
__device__ __forceinline__ float bf2f_lo(unsigned int v) {
  return __uint_as_float(v << 16);
}
__device__ __forceinline__ float bf2f_hi(unsigned int v) {
  return __uint_as_float(v & 0xFFFF0000u);
}

// ---------- scatter (blocks < SCAT_BLKS) + wbf convert (rest); cur is OFFSET-based ----------
// cur[] zeroed by hipMemsetAsync; region base is b*RCAP at use sites. k_init is gone.
__global__ __launch_bounds__(256) void k_scat(const int* __restrict__ ei,
                                              int* __restrict__ cur,
                                              int* __restrict__ ebuf,
                                              const float* __restrict__ w,
                                              unsigned short* __restrict__ wbf) {
  __shared__ int lcnt[NR];
  __shared__ int gb[NR];
  __shared__ int sc2[NR];
  const int t = threadIdx.x;

  if (blockIdx.x >= SCAT_BLKS) {
    // ---- wbf convert branch: w [k][n] row-major -> wbf [n][k] bf16 ----
    int i = (blockIdx.x - SCAT_BLKS) * 256 + t;   // 64*256 = 16384 = 128*128
    int k = i >> 7;
    int n = i & 127;
    wbf[n * 128 + k] = f2bf(w[i]);
    return;
  }

  const int e0 = blockIdx.x * SCHUNK;
  for (int i = t; i < NR; i += 256) { lcnt[i] = 0; sc2[i] = 0; }
  __syncthreads();
  // pass 1: per-range histogram (LDS atomics only); keep dst in regs for pass 2
  int myd[SCHUNK / 256];
#pragma unroll
  for (int i = 0; i < SCHUNK / 256; ++i) {
    int e = e0 + i * 256 + t;
    myd[i] = -1;
    if (e < E_EDGES) {
      int d = ei[E_EDGES + e];
      myd[i] = d;
      atomicAdd(&lcnt[d / RANGE], 1);
    }
  }
  __syncthreads();
  // claim one contiguous run per live range (returning global atomic, offset-based)
  for (int i = t; i < NR; i += 256) {
    int c = lcnt[i];
    gb[i] = c ? atomicAdd(&cur[i], c) : 0;
  }
  __syncthreads();
  // pass 2: place at region base + claimed offset + LDS rank (src re-read, coalesced)
#pragma unroll
  for (int i = 0; i < SCHUNK / 256; ++i) {
    int d = myd[i];
    if (d >= 0) {
      int e = e0 + i * 256 + t;
      int s = ei[e];
      int b = d / RANGE;
      int dl = d - b * RANGE;
      int off = gb[b] + atomicAdd(&sc2[b], 1);
      if (off < RCAP)                        // defensive clamp (statistically impossible)
        ebuf[b * RCAP + off] = s | (dl << 17);   // src: 17 bits, dst_local: 7 bits
    }
  }
}

// ---------- fused: degrees (blocks < NR, ebuf still L2-hot) + gemm (rest) ----------
__global__ __launch_bounds__(256) void k_dg(const float* __restrict__ x,
                                            const unsigned short* __restrict__ wbf,
                                            unsigned short* __restrict__ h,
                                            const int* __restrict__ ebuf,
                                            const int* __restrict__ cur,
                                            float* __restrict__ dinv) {
  __shared__ unsigned short Wl[128 * PAD];   // [n][k]
  __shared__ unsigned short Xl[64 * PAD];    // [m][k]; bounce; deg branch aliases
  const int t = threadIdx.x;

  if (blockIdx.x < NR) {
    // ---- deg branch: per-range LDS histogram (exclusive ownership, int atomics) ----
    int* hist = (int*)Xl;
    const int r = blockIdx.x;
    if (t < 128) hist[t] = 0;
    __syncthreads();
    const int lo = r * RCAP;
    const int hi = lo + min(cur[r], RCAP);
    for (int e = lo + t; e < hi; e += 256)
      atomicAdd(&hist[((unsigned)ebuf[e]) >> 17], 1);
    __syncthreads();
    if (t < RANGE) {
      int n = r * RANGE + t;
      if (n < N_NODES) dinv[n] = rsqrtf((float)(hist[t] + 1));
    }
    return;
  }

  const int row0 = (blockIdx.x - NR) * 64;

  // stage W from pre-converted bf16: 16B/lane, coalesced
#pragma unroll
  for (int i = 0; i < 8; ++i) {
    int u  = t + i * 256;        // 0..2047 16B-units
    int kg = u & 15;
    int n  = u >> 4;             // 0..127
    *(ushort8v*)&Wl[n * PAD + kg * 8] = *(const ushort8v*)&wbf[n * 128 + kg * 8];
  }
  // stage X: 64 rows x 128 k, f32 -> bf16
  const float4* x4 = (const float4*)x;
#pragma unroll
  for (int i = 0; i < 8; ++i) {
    int id = t + i * 256;
    int r  = id >> 5;
    int c4 = id & 31;
    int row = row0 + r; if (row >= N_NODES) row = N_NODES - 1;
    float4 v = x4[(long long)row * 32 + c4];
    ushort4 p;
    p.x = f2bf(v.x); p.y = f2bf(v.y); p.z = f2bf(v.z); p.w = f2bf(v.w);
    *(ushort4*)&Xl[r * PAD + c4 * 4] = p;
  }
  __syncthreads();

  const int wv   = t >> 6;
  const int l    = t & 63;
  const int quad = l >> 4;
  const int ln16 = l & 15;
  const int m0   = wv * 16;

  short8 a[4];
#pragma unroll
  for (int kt = 0; kt < 4; ++kt)
    a[kt] = *(const short8*)&Xl[(m0 + ln16) * PAD + kt * 32 + quad * 8];

#pragma unroll
  for (int nt = 0; nt < 8; ++nt) {
    f32x4 acc = {0.f, 0.f, 0.f, 0.f};
#pragma unroll
    for (int kt = 0; kt < 4; ++kt) {
      short8 b = *(const short8*)&Wl[(nt * 16 + ln16) * PAD + kt * 32 + quad * 8];
      acc = __builtin_amdgcn_mfma_f32_16x16x32_bf16(a[kt], b, acc, 0, 0, 0);
    }
#pragma unroll
    for (int r = 0; r < 4; ++r)
      Xl[(m0 + quad * 4 + r) * PAD + nt * 16 + ln16] = f2bf(acc[r]);
  }

  // coalesced writeback: 16 lanes cover one 256B h row
#pragma unroll
  for (int v = 0; v < 4; ++v) {
    int idx = v * 64 + l;        // 0..255
    int rr  = idx >> 4;
    int ch  = idx & 15;
    int row = row0 + m0 + rr;
    if (row < N_NODES)
      *(ushort8v*)&h[(long long)row * D + ch * 8] = *(const ushort8v*)&Xl[(m0 + rr) * PAD + ch * 8];
  }
}

// ---------- aggregate: LDS counting-sort by dst_local, then register accumulation ----------
// (R11/R14 verbatim; only cur is offset-based now.)
__global__ __launch_bounds__(512) void k_agg(const int* __restrict__ ebuf,
                                             const int* __restrict__ cur,
                                             const float* __restrict__ dinv,
                                             const unsigned short* __restrict__ h,
                                             const float* __restrict__ bias,
                                             float* __restrict__ out) {
  __shared__ int ssort[CAP];      // 8 KB
  __shared__ int shist[128];
  __shared__ int sscn[128];
  __shared__ int scur[128];
  const int t  = threadIdx.x;
  const int r  = blockIdx.x;
  const int wv = t >> 6;
  const int l  = t & 63;
  const unsigned int* h32 = (const unsigned int*)h;

  float a0[NPW], a1[NPW];
#pragma unroll
  for (int j = 0; j < NPW; ++j) { a0[j] = 0.f; a1[j] = 0.f; }

  const int lo = r * RCAP;
  const int m  = min(cur[r], RCAP);   // 0..2048, single chunk

  if (t < 128) shist[t] = 0;
  __syncthreads();

  // load this range's packed edges + LDS histogram of dst_local
  int pk0 = -1, pk1 = -1, pk2 = -1, pk3 = -1;
  {
    int i0 = t, i1 = t + 512, i2 = t + 1024, i3 = t + 1536;
    if (i0 < m) { pk0 = ebuf[lo + i0]; atomicAdd(&shist[((unsigned)pk0) >> 17], 1); }
    if (i1 < m) { pk1 = ebuf[lo + i1]; atomicAdd(&shist[((unsigned)pk1) >> 17], 1); }
    if (i2 < m) { pk2 = ebuf[lo + i2]; atomicAdd(&shist[((unsigned)pk2) >> 17], 1); }
    if (i3 < m) { pk3 = ebuf[lo + i3]; atomicAdd(&shist[((unsigned)pk3) >> 17], 1); }
  }
  __syncthreads();

  // inclusive scan over 128 buckets (98 live)
  if (t < 128) sscn[t] = shist[t];
  __syncthreads();
  for (int off = 1; off < 128; off <<= 1) {
    int xv = (t < 128 && t >= off) ? sscn[t - off] : 0;
    __syncthreads();
    if (t < 128) sscn[t] += xv;
    __syncthreads();
  }
  if (t < 128) scur[t] = sscn[t] - shist[t];   // exclusive start
  __syncthreads();

  // scatter src into sorted position (native int LDS atomics); strip dl here
  if (pk0 != -1) ssort[atomicAdd(&scur[((unsigned)pk0) >> 17], 1)] = pk0 & 0x1FFFF;
  if (pk1 != -1) ssort[atomicAdd(&scur[((unsigned)pk1) >> 17], 1)] = pk1 & 0x1FFFF;
  if (pk2 != -1) ssort[atomicAdd(&scur[((unsigned)pk2) >> 17], 1)] = pk2 & 0x1FFFF;
  if (pk3 != -1) ssort[atomicAdd(&scur[((unsigned)pk3) >> 17], 1)] = pk3 & 0x1FFFF;
  __syncthreads();

  // per-node register accumulation; segments from scan
#pragma unroll
  for (int j = 0; j < NPW; ++j) {
    int nl = wv + 8 * j;
    if (nl < RANGE) {
      int s1i = sscn[nl];
      int s0i = s1i - shist[nl];
      float aa0 = a0[j], aa1 = a1[j];
#pragma unroll 4
      for (int e = s0i; e < s1i; ++e) {
        int s = ssort[e];                      // wave-uniform LDS broadcast
        float wgt = dinv[s];
        unsigned u = h32[(long long)s * 64 + l];
        aa0 = fmaf(bf2f_lo(u), wgt, aa0);
        aa1 = fmaf(bf2f_hi(u), wgt, aa1);
      }
      a0[j] = aa0; a1[j] = aa1;
    }
  }

  // finalize: out = dinv_n*(acc + dinv_n*h_n) + bias, relu, dropout
  // dv recomputed from shist (own-range degree) - no global dinv re-read
#pragma unroll
  for (int j = 0; j < NPW; ++j) {
    int nl = wv + 8 * j;
    if (nl >= RANGE) continue;
    int n = r * RANGE + nl;
    if (n >= N_NODES) continue;
    float dv = rsqrtf((float)(shist[nl] + 1));
    unsigned hv = h32[(long long)n * 64 + l];
    float v0 = (a0[j] + bf2f_lo(hv) * dv) * dv;
    float v1 = (a1[j] + bf2f_hi(hv) * dv) * dv;
    float2 bb = ((const float2*)bias)[l];
    float r0 = fmaxf(v0 + bb.x, 0.f);
    float r1 = fmaxf(v1 + bb.y, 0.f);
    unsigned i0 = (unsigned)n * 128u + (unsigned)(2 * l);
    unsigned b0 = threefry_bits(i0);
    unsigned b1 = threefry_bits(i0 + 1u);
    float2 res;
    res.x = (b0 & 0x80000000u) ? 0.0f : r0 * 2.0f;
    res.y = (b1 & 0x80000000u) ? 0.0f : r1 * 2.0f;
    ((float2*)out)[(long long)n * 64 + l] = res;
  }
}

extern "C" void kernel_launch(void* const* d_in, const int* in_sizes, int n_in,
                              void* d_out, int out_size, void* d_ws, size_t ws_size,
                              hipStream_t stream) {
  const float* x    = (const float*)d_in[0];
  const int*   ei   = (const int*)d_in[1];
  const float* w    = (const float*)d_in[2];
  const float* bias = (const float*)d_in[3];
  float* out = (float*)d_out;

  char* p = (char*)d_ws;
  unsigned short* h   = (unsigned short*)p;  p += (size_t)N_NODES * D * 2;   // 25.6 MB
  unsigned short* wbf = (unsigned short*)p;  p += 128 * 128 * 2;             // 32 KB
  float* dinv = (float*)p;                   p += (size_t)(NR * RANGE) * 4;  // 401 KB
  int* cur    = (int*)p;                     p += NR * 4;                    // 4 KB
  int* ebuf   = (int*)p;                     p += (size_t)NR * RCAP * 4;     // 8.4 MB

  hipMemsetAsync(cur, 0, NR * 4, stream);
  k_scat<<<SCAT_BLKS + WCONV_BLKS, 256, 0, stream>>>(ei, cur, ebuf, w, wbf);
  k_dg<<<NR + GEMM_BLKS, 256, 0, stream>>>(x, wbf, h, ebuf, cur, dinv);
  k_agg<<<NR, 512, 0, stream>>>(ebuf, cur, dinv, h, bias, out);
}